// Round 4
// baseline (238.645 us; speedup 1.0000x reference)
//
#include <hip/hip_runtime.h>
#include <stdint.h>

#define NCOL 16
#define NB   1024            // exactly 4 blocks/CU * 256 CUs -> all co-resident
typedef float v4f __attribute__((ext_vector_type(4)));

// ---- module-lifetime device state (never in d_ws -> immune to 0xAA poison) ----
__device__ unsigned long long g_arrive = 0;   // monotonic ticket counter
__device__ uint32_t g_mm[2 * NCOL];           // [0..15] min keys, [16..31] max keys

// ---- ordered-uint mapping for float atomic min/max ----
__device__ __forceinline__ uint32_t fkey(float f) {
    uint32_t u = __float_as_uint(f);
    return (u & 0x80000000u) ? ~u : (u | 0x80000000u);
}
__device__ __forceinline__ float fkey_dec(uint32_t k) {
    uint32_t u = (k & 0x80000000u) ? (k ^ 0x80000000u) : ~k;
    return __uint_as_float(u);
}

// Grid barrier via monotonic tickets: correct for any number of sequential
// launches (targets are successive multiples of NB), requires all NB blocks
// resident (guaranteed: grid == occupancy capacity under launch_bounds).
__device__ __forceinline__ void grid_barrier() {
    __syncthreads();
    if (threadIdx.x == 0) {
        unsigned long long ticket =
            __hip_atomic_fetch_add(&g_arrive, 1ull, __ATOMIC_ACQ_REL,
                                   __HIP_MEMORY_SCOPE_AGENT) + 1ull;
        unsigned long long target = ((ticket + (NB - 1)) / NB) * NB;
        while (__hip_atomic_load(&g_arrive, __ATOMIC_ACQUIRE,
                                 __HIP_MEMORY_SCOPE_AGENT) < target) {
            __builtin_amdgcn_s_sleep(8);
        }
    }
    __syncthreads();
}

// out = w0*xn + w1*xn^2 + w2*xn^3 + w3*exp(xn) + w4*log(|xn|+1) + w5*sqrt(|xn|)
//     + w6*tanh(xn) + w7*sin(xn) + w8*|xn| + bias      (xn in [-1,1] -> clips no-op)
__device__ __forceinline__ float eval_basis(float xn, const float* w, float b) {
    float ax = fabsf(xn);
    float x2 = xn * xn;
    float x3 = x2 * xn;
    float e  = __expf(xn);
    float e2 = e * e;                               // exp(2*xn)
    float t  = 1.0f - 2.0f * __frcp_rn(e2 + 1.0f);  // tanh
    float l  = __logf(ax + 1.0f);
    float sq = __fsqrt_rn(ax);
    float sn = __sinf(xn);
    float r = b;
    r = fmaf(w[0], xn, r);
    r = fmaf(w[1], x2, r);
    r = fmaf(w[2], x3, r);
    r = fmaf(w[3], e,  r);
    r = fmaf(w[4], l,  r);
    r = fmaf(w[5], sq, r);
    r = fmaf(w[6], t,  r);
    r = fmaf(w[7], sn, r);
    r = fmaf(w[8], ax, r);
    return r;
}

// Single persistent kernel: init -> barrier -> column min/max -> barrier ->
// normalize + basis transform (NT stores keep x resident in L3 for phase 2).
__global__ void __launch_bounds__(256, 4) fused_kernel(
        const v4f* __restrict__ x, v4f* __restrict__ out,
        const float* __restrict__ wts, const float* __restrict__ bias, int n4) {
    int tid = blockIdx.x * blockDim.x + threadIdx.x;
    int stride = NB * 256;               // multiple of 4 -> column group fixed

    // ---- phase 0: block 0 inits the min/max slots at the coherence point ----
    if (blockIdx.x == 0 && threadIdx.x < 2 * NCOL) {
        uint32_t v = (threadIdx.x < NCOL) ? fkey(INFINITY) : fkey(-INFINITY);
        __hip_atomic_store(&g_mm[threadIdx.x], v, __ATOMIC_RELAXED,
                           __HIP_MEMORY_SCOPE_AGENT);
    }
    grid_barrier();

    // ---- phase 1: column-wise min/max over x[N,16], read as float4 ----
    // float4 index i covers columns (4*i)%16..+3; stride%4==0 so each thread's
    // column group g=(tid&3)*4 is loop-invariant.
    {
        float mn0 = INFINITY, mn1 = INFINITY, mn2 = INFINITY, mn3 = INFINITY;
        float mx0 = -INFINITY, mx1 = -INFINITY, mx2 = -INFINITY, mx3 = -INFINITY;
        for (int i = tid; i < n4; i += stride) {
            v4f v = x[i];                // regular load: warms L2/L3 for phase 2
            mn0 = fminf(mn0, v.x); mx0 = fmaxf(mx0, v.x);
            mn1 = fminf(mn1, v.y); mx1 = fmaxf(mx1, v.y);
            mn2 = fminf(mn2, v.z); mx2 = fmaxf(mx2, v.z);
            mn3 = fminf(mn3, v.w); mx3 = fmaxf(mx3, v.w);
        }
        #pragma unroll
        for (int off = 4; off < 64; off <<= 1) {
            mn0 = fminf(mn0, __shfl_xor(mn0, off)); mx0 = fmaxf(mx0, __shfl_xor(mx0, off));
            mn1 = fminf(mn1, __shfl_xor(mn1, off)); mx1 = fmaxf(mx1, __shfl_xor(mx1, off));
            mn2 = fminf(mn2, __shfl_xor(mn2, off)); mx2 = fmaxf(mx2, __shfl_xor(mx2, off));
            mn3 = fminf(mn3, __shfl_xor(mn3, off)); mx3 = fmaxf(mx3, __shfl_xor(mx3, off));
        }
        __shared__ float smn[4][NCOL], smx[4][NCOL];
        int wave = threadIdx.x >> 6;
        int lane = threadIdx.x & 63;
        if (lane < 4) {       // lane l holds the full wave reduction for group l
            int g = lane * 4;
            smn[wave][g + 0] = mn0; smx[wave][g + 0] = mx0;
            smn[wave][g + 1] = mn1; smx[wave][g + 1] = mx1;
            smn[wave][g + 2] = mn2; smx[wave][g + 2] = mx2;
            smn[wave][g + 3] = mn3; smx[wave][g + 3] = mx3;
        }
        __syncthreads();
        if (threadIdx.x < NCOL) {
            int c = threadIdx.x;
            float m = fminf(fminf(smn[0][c], smn[1][c]), fminf(smn[2][c], smn[3][c]));
            float M = fmaxf(fmaxf(smx[0][c], smx[1][c]), fmaxf(smx[2][c], smx[3][c]));
            atomicMin(&g_mm[c], fkey(m));            // device-scope by default
            atomicMax(&g_mm[NCOL + c], fkey(M));
        }
    }
    grid_barrier();

    // ---- phase 2: normalize + basis transform ----
    __shared__ float s_scale[NCOL], s_off[NCOL], s_w[9];
    if (threadIdx.x < NCOL) {
        // atomic loads: bypass any stale L1/L2 line from a previous launch
        float mn = fkey_dec(__hip_atomic_load(&g_mm[threadIdx.x],
                        __ATOMIC_RELAXED, __HIP_MEMORY_SCOPE_AGENT));
        float mx = fkey_dec(__hip_atomic_load(&g_mm[NCOL + threadIdx.x],
                        __ATOMIC_RELAXED, __HIP_MEMORY_SCOPE_AGENT));
        float r = mx - mn;
        if (r == 0.0f) r = 1.0f;
        s_scale[threadIdx.x] = 2.0f / r;
        s_off[threadIdx.x]   = -2.0f * mn / r - 1.0f;
    }
    if (threadIdx.x < 9) s_w[threadIdx.x] = wts[threadIdx.x];
    __syncthreads();

    int g = (tid & 3) * 4;
    float sc0 = s_scale[g + 0], of0 = s_off[g + 0];
    float sc1 = s_scale[g + 1], of1 = s_off[g + 1];
    float sc2 = s_scale[g + 2], of2 = s_off[g + 2];
    float sc3 = s_scale[g + 3], of3 = s_off[g + 3];
    float w[9];
    #pragma unroll
    for (int k = 0; k < 9; ++k) w[k] = s_w[k];
    float b = bias[0];

    for (int i = tid; i < n4; i += stride) {
        v4f v = x[i];
        v4f o;
        o.x = eval_basis(fmaf(v.x, sc0, of0), w, b);
        o.y = eval_basis(fmaf(v.y, sc1, of1), w, b);
        o.z = eval_basis(fmaf(v.z, sc2, of2), w, b);
        o.w = eval_basis(fmaf(v.w, sc3, of3), w, b);
        // nontemporal: out is never re-read; don't evict x from L2/L3
        __builtin_nontemporal_store(o, &out[i]);
    }
}

extern "C" void kernel_launch(void* const* d_in, const int* in_sizes, int n_in,
                              void* d_out, int out_size, void* d_ws, size_t ws_size,
                              hipStream_t stream) {
    const v4f* x      = (const v4f*)d_in[0];
    const float* wts  = (const float*)d_in[1];
    const float* bias = (const float*)d_in[2];
    v4f* out = (v4f*)d_out;

    int n  = in_sizes[0];       // N * 16 elements
    int n4 = n / 4;             // exact

    fused_kernel<<<NB, 256, 0, stream>>>(x, out, wts, bias, n4);
}

// Round 5
// 153.031 us; speedup vs baseline: 1.5595x; 1.5595x over previous
//
#include <hip/hip_runtime.h>
#include <stdint.h>

#define NCOL 16
typedef float v4f __attribute__((ext_vector_type(4)));

// ---- ordered-uint mapping for float atomic min/max ----
// fkey is monotonic: a<b  <=>  fkey(a)<fkey(b). Identities:
//   atomicMin slots init 0xFFFFFFFF (decodes to NaN-max, any real key smaller)
//   atomicMax slots init 0x00000000 (decodes to NaN-min, any real key larger)
// -> both identities are pure byte patterns reachable with hipMemsetAsync.
__device__ __forceinline__ uint32_t fkey(float f) {
    uint32_t u = __float_as_uint(f);
    return (u & 0x80000000u) ? ~u : (u | 0x80000000u);
}
__device__ __forceinline__ float fkey_dec(uint32_t k) {
    uint32_t u = (k & 0x80000000u) ? (k ^ 0x80000000u) : ~k;
    return __uint_as_float(u);
}

// Column-wise min/max over x[N,16] row-major, read as float4 with 2-way ILP:
// each thread streams x[i] and x[i+half] back-to-back (2 independent loads in
// flight) into separate accumulator sets. half = n4/2 is a multiple of 4, so
// both halves map to the same column group g=(tid&3)*4.
__global__ void __launch_bounds__(256) colreduce(const v4f* __restrict__ x,
                                                 uint32_t* __restrict__ mm, int n4) {
    int tid = blockIdx.x * blockDim.x + threadIdx.x;
    int stride = gridDim.x * blockDim.x;   // multiple of 4
    int half = n4 >> 1;                    // n4 = 4e6 -> half % 4 == 0
    float amn0 = INFINITY, amn1 = INFINITY, amn2 = INFINITY, amn3 = INFINITY;
    float amx0 = -INFINITY, amx1 = -INFINITY, amx2 = -INFINITY, amx3 = -INFINITY;
    float bmn0 = INFINITY, bmn1 = INFINITY, bmn2 = INFINITY, bmn3 = INFINITY;
    float bmx0 = -INFINITY, bmx1 = -INFINITY, bmx2 = -INFINITY, bmx3 = -INFINITY;
    for (int i = tid; i < half; i += stride) {
        v4f a = x[i];
        v4f b = x[i + half];
        amn0 = fminf(amn0, a.x); amx0 = fmaxf(amx0, a.x);
        amn1 = fminf(amn1, a.y); amx1 = fmaxf(amx1, a.y);
        amn2 = fminf(amn2, a.z); amx2 = fmaxf(amx2, a.z);
        amn3 = fminf(amn3, a.w); amx3 = fmaxf(amx3, a.w);
        bmn0 = fminf(bmn0, b.x); bmx0 = fmaxf(bmx0, b.x);
        bmn1 = fminf(bmn1, b.y); bmx1 = fmaxf(bmx1, b.y);
        bmn2 = fminf(bmn2, b.z); bmx2 = fmaxf(bmx2, b.z);
        bmn3 = fminf(bmn3, b.w); bmx3 = fmaxf(bmx3, b.w);
    }
    if (tid == 0 && (n4 & 1)) {            // odd-n4 tail (not hit for N=1e6)
        v4f t = x[n4 - 1];
        amn0 = fminf(amn0, t.x); amx0 = fmaxf(amx0, t.x);
        amn1 = fminf(amn1, t.y); amx1 = fmaxf(amx1, t.y);
        amn2 = fminf(amn2, t.z); amx2 = fmaxf(amx2, t.z);
        amn3 = fminf(amn3, t.w); amx3 = fmaxf(amx3, t.w);
    }
    float mn0 = fminf(amn0, bmn0), mx0 = fmaxf(amx0, bmx0);
    float mn1 = fminf(amn1, bmn1), mx1 = fmaxf(amx1, bmx1);
    float mn2 = fminf(amn2, bmn2), mx2 = fmaxf(amx2, bmx2);
    float mn3 = fminf(amn3, bmn3), mx3 = fmaxf(amx3, bmx3);
    // Butterfly across the 16 lanes sharing the same (lane&3) column group.
    #pragma unroll
    for (int off = 4; off < 64; off <<= 1) {
        mn0 = fminf(mn0, __shfl_xor(mn0, off)); mx0 = fmaxf(mx0, __shfl_xor(mx0, off));
        mn1 = fminf(mn1, __shfl_xor(mn1, off)); mx1 = fmaxf(mx1, __shfl_xor(mx1, off));
        mn2 = fminf(mn2, __shfl_xor(mn2, off)); mx2 = fmaxf(mx2, __shfl_xor(mx2, off));
        mn3 = fminf(mn3, __shfl_xor(mn3, off)); mx3 = fmaxf(mx3, __shfl_xor(mx3, off));
    }
    __shared__ float smn[4][NCOL], smx[4][NCOL];
    int wave = threadIdx.x >> 6;
    int lane = threadIdx.x & 63;
    if (lane < 4) {           // lane l holds the full wave reduction for group l
        int g = lane * 4;
        smn[wave][g + 0] = mn0; smx[wave][g + 0] = mx0;
        smn[wave][g + 1] = mn1; smx[wave][g + 1] = mx1;
        smn[wave][g + 2] = mn2; smx[wave][g + 2] = mx2;
        smn[wave][g + 3] = mn3; smx[wave][g + 3] = mx3;
    }
    __syncthreads();
    if (threadIdx.x < NCOL) {
        int c = threadIdx.x;
        float m = fminf(fminf(smn[0][c], smn[1][c]), fminf(smn[2][c], smn[3][c]));
        float M = fmaxf(fmaxf(smx[0][c], smx[1][c]), fmaxf(smx[2][c], smx[3][c]));
        atomicMin(&mm[c], fkey(m));
        atomicMax(&mm[NCOL + c], fkey(M));
    }
}

// out = w0*xn + w1*xn^2 + w2*xn^3 + w3*exp(xn) + w4*log(|xn|+1) + w5*sqrt(|xn|)
//     + w6*tanh(xn) + w7*sin(xn) + w8*|xn| + bias      (xn in [-1,1] -> clips no-op)
__device__ __forceinline__ float eval_basis(float xn, const float* w, float b) {
    float ax = fabsf(xn);
    float x2 = xn * xn;
    float x3 = x2 * xn;
    float e  = __expf(xn);
    float e2 = e * e;                               // exp(2*xn)
    float t  = 1.0f - 2.0f * __frcp_rn(e2 + 1.0f);  // tanh
    float l  = __logf(ax + 1.0f);
    float sq = __fsqrt_rn(ax);
    float sn = __sinf(xn);
    float r = b;
    r = fmaf(w[0], xn, r);
    r = fmaf(w[1], x2, r);
    r = fmaf(w[2], x3, r);
    r = fmaf(w[3], e,  r);
    r = fmaf(w[4], l,  r);
    r = fmaf(w[5], sq, r);
    r = fmaf(w[6], t,  r);
    r = fmaf(w[7], sn, r);
    r = fmaf(w[8], ax, r);
    return r;
}

// One float4 per thread (one-shot): max TLP, no loop-carried vmcnt chains.
__global__ void __launch_bounds__(256) feature_kernel(const v4f* __restrict__ x,
                                                      v4f* __restrict__ out,
                                                      const uint32_t* __restrict__ mm,
                                                      const float* __restrict__ wts,
                                                      const float* __restrict__ bias,
                                                      int n4) {
    __shared__ float s_scale[NCOL], s_off[NCOL], s_w[9];
    if (threadIdx.x < NCOL) {
        float mn = fkey_dec(mm[threadIdx.x]);
        float mx = fkey_dec(mm[NCOL + threadIdx.x]);
        float r = mx - mn;
        if (r == 0.0f) r = 1.0f;
        s_scale[threadIdx.x] = 2.0f / r;
        s_off[threadIdx.x]   = -2.0f * mn / r - 1.0f;
    }
    if (threadIdx.x < 9) s_w[threadIdx.x] = wts[threadIdx.x];
    __syncthreads();

    int tid = blockIdx.x * blockDim.x + threadIdx.x;
    if (tid >= n4) return;
    int g = (tid & 3) * 4;                 // this thread's 4 columns
    float sc0 = s_scale[g + 0], of0 = s_off[g + 0];
    float sc1 = s_scale[g + 1], of1 = s_off[g + 1];
    float sc2 = s_scale[g + 2], of2 = s_off[g + 2];
    float sc3 = s_scale[g + 3], of3 = s_off[g + 3];
    float w[9];
    #pragma unroll
    for (int k = 0; k < 9; ++k) w[k] = s_w[k];
    float b = bias[0];

    v4f v = x[tid];
    v4f o;
    o.x = eval_basis(fmaf(v.x, sc0, of0), w, b);
    o.y = eval_basis(fmaf(v.y, sc1, of1), w, b);
    o.z = eval_basis(fmaf(v.z, sc2, of2), w, b);
    o.w = eval_basis(fmaf(v.w, sc3, of3), w, b);
    // nontemporal: out is never re-read; don't evict x from L2/L3
    __builtin_nontemporal_store(o, &out[tid]);
}

extern "C" void kernel_launch(void* const* d_in, const int* in_sizes, int n_in,
                              void* d_out, int out_size, void* d_ws, size_t ws_size,
                              hipStream_t stream) {
    const float* x    = (const float*)d_in[0];
    const float* wts  = (const float*)d_in[1];
    const float* bias = (const float*)d_in[2];
    float* out = (float*)d_out;
    uint32_t* mm = (uint32_t*)d_ws;

    int n  = in_sizes[0];       // N * 16 elements
    int n4 = n / 4;             // exact: 16e6 / 4

    // init min/max identity keys via memset (replaces a kernel dispatch):
    // min slots [0..15] -> 0xFFFFFFFF (largest key), max slots [16..31] -> 0x0
    hipMemsetAsync(mm, 0xFF, NCOL * sizeof(uint32_t), stream);
    hipMemsetAsync(mm + NCOL, 0x00, NCOL * sizeof(uint32_t), stream);

    colreduce<<<2048, 256, 0, stream>>>((const v4f*)x, mm, n4);
    int blocks = (n4 + 255) / 256;
    feature_kernel<<<blocks, 256, 0, stream>>>((const v4f*)x, (v4f*)out, mm,
                                               wts, bias, n4);
}

// Round 6
// 149.174 us; speedup vs baseline: 1.5998x; 1.0259x over previous
//
#include <hip/hip_runtime.h>
#include <stdint.h>

#define NCOL 16
typedef float v4f __attribute__((ext_vector_type(4)));

// ---- ordered-uint mapping for float atomic min/max ----
// fkey is monotonic: a<b <=> fkey(a)<fkey(b).
// Min slot:  atomicMin(fkey(f)),  identity 0xFFFFFFFF.
// Max slot:  atomicMin(fkey(-f)), identity 0xFFFFFFFF  (order-reversed map),
//            decode as -fkey_dec(k).
// -> ALL 32 slots share identity 0xFFFFFFFF: a single 128 B hipMemsetAsync.
__device__ __forceinline__ uint32_t fkey(float f) {
    uint32_t u = __float_as_uint(f);
    return (u & 0x80000000u) ? ~u : (u | 0x80000000u);
}
__device__ __forceinline__ float fkey_dec(uint32_t k) {
    uint32_t u = (k & 0x80000000u) ? (k ^ 0x80000000u) : ~k;
    return __uint_as_float(u);
}

// Column-wise min/max over x[N,16] row-major, read as float4.
// Global float4 index i covers columns (4*i)%16 .. +3; with stride a multiple
// of 4 float4s, each thread's column group g=(tid&3)*4 is loop-invariant.
__global__ void __launch_bounds__(256) colreduce(const v4f* __restrict__ x,
                                                 uint32_t* __restrict__ mm, int n4) {
    int tid = blockIdx.x * blockDim.x + threadIdx.x;
    int stride = gridDim.x * blockDim.x;   // 256-thread blocks -> multiple of 4
    float mn0 = INFINITY, mn1 = INFINITY, mn2 = INFINITY, mn3 = INFINITY;
    float mx0 = -INFINITY, mx1 = -INFINITY, mx2 = -INFINITY, mx3 = -INFINITY;
    for (int i = tid; i < n4; i += stride) {
        v4f v = x[i];   // regular load: populates L2/L3 so pass 2 hits L3
        mn0 = fminf(mn0, v.x); mx0 = fmaxf(mx0, v.x);
        mn1 = fminf(mn1, v.y); mx1 = fmaxf(mx1, v.y);
        mn2 = fminf(mn2, v.z); mx2 = fmaxf(mx2, v.z);
        mn3 = fminf(mn3, v.w); mx3 = fmaxf(mx3, v.w);
    }
    // Butterfly across the 16 lanes sharing the same (lane&3) column group.
    #pragma unroll
    for (int off = 4; off < 64; off <<= 1) {
        mn0 = fminf(mn0, __shfl_xor(mn0, off)); mx0 = fmaxf(mx0, __shfl_xor(mx0, off));
        mn1 = fminf(mn1, __shfl_xor(mn1, off)); mx1 = fmaxf(mx1, __shfl_xor(mx1, off));
        mn2 = fminf(mn2, __shfl_xor(mn2, off)); mx2 = fmaxf(mx2, __shfl_xor(mx2, off));
        mn3 = fminf(mn3, __shfl_xor(mn3, off)); mx3 = fmaxf(mx3, __shfl_xor(mx3, off));
    }
    __shared__ float smn[4][NCOL], smx[4][NCOL];
    int wave = threadIdx.x >> 6;
    int lane = threadIdx.x & 63;
    if (lane < 4) {           // lane l holds the full wave reduction for group l
        int g = lane * 4;
        smn[wave][g + 0] = mn0; smx[wave][g + 0] = mx0;
        smn[wave][g + 1] = mn1; smx[wave][g + 1] = mx1;
        smn[wave][g + 2] = mn2; smx[wave][g + 2] = mx2;
        smn[wave][g + 3] = mn3; smx[wave][g + 3] = mx3;
    }
    __syncthreads();
    if (threadIdx.x < NCOL) {
        int c = threadIdx.x;
        float m = fminf(fminf(smn[0][c], smn[1][c]), fminf(smn[2][c], smn[3][c]));
        float M = fmaxf(fmaxf(smx[0][c], smx[1][c]), fmaxf(smx[2][c], smx[3][c]));
        atomicMin(&mm[c], fkey(m));
        atomicMin(&mm[NCOL + c], fkey(-M));   // reversed map: max via atomicMin
    }
}

// out = w0*xn + w1*xn^2 + w2*xn^3 + w3*exp(xn) + w4*log(|xn|+1) + w5*sqrt(|xn|)
//     + w6*tanh(xn) + w7*sin(xn) + w8*|xn| + bias      (xn in [-1,1] -> clips no-op)
__device__ __forceinline__ float eval_basis(float xn, const float* w, float b) {
    float ax = fabsf(xn);
    float x2 = xn * xn;
    float x3 = x2 * xn;
    float e  = __expf(xn);
    float e2 = e * e;                               // exp(2*xn)
    float t  = 1.0f - 2.0f * __frcp_rn(e2 + 1.0f);  // tanh
    float l  = __logf(ax + 1.0f);
    float sq = __fsqrt_rn(ax);
    float sn = __sinf(xn);
    float r = b;
    r = fmaf(w[0], xn, r);
    r = fmaf(w[1], x2, r);
    r = fmaf(w[2], x3, r);
    r = fmaf(w[3], e,  r);
    r = fmaf(w[4], l,  r);
    r = fmaf(w[5], sq, r);
    r = fmaf(w[6], t,  r);
    r = fmaf(w[7], sn, r);
    r = fmaf(w[8], ax, r);
    return r;
}

__global__ void __launch_bounds__(256) feature_kernel(const v4f* __restrict__ x,
                                                      v4f* __restrict__ out,
                                                      const uint32_t* __restrict__ mm,
                                                      const float* __restrict__ wts,
                                                      const float* __restrict__ bias,
                                                      int n4) {
    __shared__ float s_scale[NCOL], s_off[NCOL], s_w[9];
    if (threadIdx.x < NCOL) {
        float mn = fkey_dec(mm[threadIdx.x]);
        float mx = -fkey_dec(mm[NCOL + threadIdx.x]);   // reversed-map decode
        float r = mx - mn;
        if (r == 0.0f) r = 1.0f;
        s_scale[threadIdx.x] = 2.0f / r;
        s_off[threadIdx.x]   = -2.0f * mn / r - 1.0f;
    }
    if (threadIdx.x < 9) s_w[threadIdx.x] = wts[threadIdx.x];
    __syncthreads();

    int tid = blockIdx.x * blockDim.x + threadIdx.x;
    int stride = gridDim.x * blockDim.x;   // multiple of 4 -> column group fixed
    int g = (tid & 3) * 4;                 // this thread's 4 columns
    float sc0 = s_scale[g + 0], of0 = s_off[g + 0];
    float sc1 = s_scale[g + 1], of1 = s_off[g + 1];
    float sc2 = s_scale[g + 2], of2 = s_off[g + 2];
    float sc3 = s_scale[g + 3], of3 = s_off[g + 3];
    float w[9];
    #pragma unroll
    for (int k = 0; k < 9; ++k) w[k] = s_w[k];
    float b = bias[0];

    for (int i = tid; i < n4; i += stride) {
        v4f v = x[i];
        v4f o;
        o.x = eval_basis(fmaf(v.x, sc0, of0), w, b);
        o.y = eval_basis(fmaf(v.y, sc1, of1), w, b);
        o.z = eval_basis(fmaf(v.z, sc2, of2), w, b);
        o.w = eval_basis(fmaf(v.w, sc3, of3), w, b);
        // nontemporal: out is never re-read; don't evict x from L2/L3
        __builtin_nontemporal_store(o, &out[i]);
    }
}

extern "C" void kernel_launch(void* const* d_in, const int* in_sizes, int n_in,
                              void* d_out, int out_size, void* d_ws, size_t ws_size,
                              hipStream_t stream) {
    const float* x    = (const float*)d_in[0];
    const float* wts  = (const float*)d_in[1];
    const float* bias = (const float*)d_in[2];
    float* out = (float*)d_out;
    uint32_t* mm = (uint32_t*)d_ws;

    int n  = in_sizes[0];       // N * 16 elements
    int n4 = n / 4;             // exact: 16e6 / 4

    // single init: all 32 slots share identity 0xFFFFFFFF (see fkey comment)
    hipMemsetAsync(mm, 0xFF, 2 * NCOL * sizeof(uint32_t), stream);

    colreduce<<<2048, 256, 0, stream>>>((const v4f*)x, mm, n4);
    feature_kernel<<<4096, 256, 0, stream>>>((const v4f*)x, (v4f*)out, mm,
                                             wts, bias, n4);
}